// Round 3
// baseline (35.543 us; speedup 1.0000x reference)
//
#include <hip/hip_runtime.h>

// NcutLoss: N=4, K=8, C=3, H=W=1024, S=1000, R=5, P=81 disk points.
// loss = N*K - sum_{n,k} num[n,k]/den[n,k]
//   num[n,k] = sum_{s,p} wgt[n,s,p]*q[n,k,s,p]*pc[n,k,s]
//   den[n,k] = sum_s pc[n,k,s] * sum_p wgt[n,s,p]
//   wgt = exp(-d2/SIGMA_I^2 - (di^2+dj^2)/SIGMA_X^2), d2 = sum_c (img_n-img_c)^2
//
// R2 change: no global atomics, no zero kernel (2 graph nodes). Each block
// writes 16 partials to its own d_ws slot; pv loads hoisted to overlap gather.

constexpr int P = 81;
constexpr int WW = 1024;
constexpr size_t HW = (size_t)1024 * 1024;
constexpr int NN = 4, KK = 8, CC = 3;
constexpr float INV_SI2 = 1.0f / 100.0f;  // 1/SIGMA_I^2
constexpr float INV_SX2 = 1.0f / 16.0f;   // 1/SIGMA_X^2

// Disk offsets, row-major over di=-5..5 (order irrelevant: all sums over p).
__device__ __constant__ signed char c_di[P] = {
    -5,
    -4,-4,-4,-4,-4,-4,-4,
    -3,-3,-3,-3,-3,-3,-3,-3,-3,
    -2,-2,-2,-2,-2,-2,-2,-2,-2,
    -1,-1,-1,-1,-1,-1,-1,-1,-1,
     0, 0, 0, 0, 0, 0, 0, 0, 0, 0, 0,
     1, 1, 1, 1, 1, 1, 1, 1, 1,
     2, 2, 2, 2, 2, 2, 2, 2, 2,
     3, 3, 3, 3, 3, 3, 3, 3, 3,
     4, 4, 4, 4, 4, 4, 4,
     5
};
__device__ __constant__ signed char c_dj[P] = {
     0,
    -3,-2,-1, 0, 1, 2, 3,
    -4,-3,-2,-1, 0, 1, 2, 3, 4,
    -4,-3,-2,-1, 0, 1, 2, 3, 4,
    -4,-3,-2,-1, 0, 1, 2, 3, 4,
    -5,-4,-3,-2,-1, 0, 1, 2, 3, 4, 5,
    -4,-3,-2,-1, 0, 1, 2, 3, 4,
    -4,-3,-2,-1, 0, 1, 2, 3, 4,
    -4,-3,-2,-1, 0, 1, 2, 3, 4,
    -3,-2,-1, 0, 1, 2, 3,
     0
};

__global__ __launch_bounds__(256) void ncut_accum(
    const float* __restrict__ pred,   // (N,K,H,W)
    const float* __restrict__ imgs,   // (N,C,H,W)
    const long long* __restrict__ hs, // (S,)
    const long long* __restrict__ wsm,// (S,)
    float* __restrict__ partial,      // (N, gridX, 16)
    int S, int gridX)
{
    __shared__ float lbin[16];        // num[8], den[8] for this block
    const int tid  = threadIdx.x;
    const int lane = tid & 63;
    const int wave = tid >> 6;
    if (tid < 16) lbin[tid] = 0.0f;
    __syncthreads();

    const int n = blockIdx.y;
    const int s = blockIdx.x * 4 + wave;
    if (s < S) {
        const int h = (int)hs[s] + 5;
        const int w = (int)wsm[s] + 5;
        const float* img_n = imgs + (size_t)n * CC * HW;
        const size_t coff = (size_t)h * WW + w;
        const float* pn = pred + (size_t)n * KK * HW;

        // Hoisted center-pred loads: lanes 0..15 fetch pv for k = lane&7,
        // latency overlapped with the neighborhood gather below.
        float pv = 0.0f;
        if (lane < 16) pv = pn[(size_t)(lane & 7) * HW + coff];

        const float c0 = img_n[coff];
        const float c1 = img_n[HW + coff];
        const float c2 = img_n[2 * HW + coff];

        float qw[KK] = {0.f,0.f,0.f,0.f,0.f,0.f,0.f,0.f};
        float wsum = 0.0f;

        #pragma unroll
        for (int rep = 0; rep < 2; ++rep) {
            const int p = lane + rep * 64;
            if (p < P) {
                const int di = (int)c_di[p];
                const int dj = (int)c_dj[p];
                const size_t off = (size_t)(h + di) * WW + (w + dj);
                const float d0 = img_n[off]          - c0;
                const float d1 = img_n[HW + off]     - c1;
                const float d2 = img_n[2 * HW + off] - c2;
                const float r2 = (float)(di * di + dj * dj);
                const float wgt = __expf(-((d0*d0 + d1*d1 + d2*d2) * INV_SI2
                                           + r2 * INV_SX2));
                wsum += wgt;
                const float* qb = pn + off;
                #pragma unroll
                for (int k = 0; k < KK; ++k)
                    qw[k] += wgt * qb[(size_t)k * HW];
            }
        }

        // 64-lane butterfly reduction of 9 values; all lanes end with totals.
        #pragma unroll
        for (int off = 32; off; off >>= 1) {
            wsum += __shfl_xor(wsum, off);
            #pragma unroll
            for (int k = 0; k < KK; ++k)
                qw[k] += __shfl_xor(qw[k], off);
        }

        // Lanes 0..15 each contribute one value: t<8 -> pv*qw[t], t>=8 -> pv*wsum
        if (lane < 16) {
            const int t = lane;
            float q = qw[0];
            #pragma unroll
            for (int j = 1; j < KK; ++j)
                if ((t & 7) == j) q = qw[j];
            const float val = (t < 8) ? q : wsum;
            atomicAdd(&lbin[t], pv * val);
        }
    }
    __syncthreads();
    if (tid < 16)
        partial[((size_t)n * gridX + blockIdx.x) * 16 + tid] = lbin[tid];
}

__global__ __launch_bounds__(256) void ncut_final(
    const float* __restrict__ partial, float* __restrict__ out, int gridX)
{
    __shared__ float L[64];
    const int tid  = threadIdx.x;     // 256 threads
    const int oidx = tid >> 2;        // 0..63: n = oidx>>4, t = oidx&15
    const int sub  = tid & 3;
    const int n = oidx >> 4, t = oidx & 15;

    float v = 0.0f;
    for (int bx = sub; bx < gridX; bx += 4)
        v += partial[((size_t)n * gridX + bx) * 16 + t];
    v += __shfl_xor(v, 1);
    v += __shfl_xor(v, 2);
    if (sub == 0) L[oidx] = v;
    __syncthreads();

    float r = 0.0f;
    if (tid < 32) {
        const int nn = tid >> 3, k = tid & 7;
        r = L[nn * 16 + k] / L[nn * 16 + 8 + k];
    }
    #pragma unroll
    for (int off = 32; off; off >>= 1)
        r += __shfl_xor(r, off);
    if (tid == 0) out[0] = (float)(NN * KK) - r;
}

extern "C" void kernel_launch(void* const* d_in, const int* in_sizes, int n_in,
                              void* d_out, int out_size, void* d_ws, size_t ws_size,
                              hipStream_t stream) {
    const float* pred     = (const float*)d_in[0];
    const float* imgs     = (const float*)d_in[1];
    const long long* hs   = (const long long*)d_in[2];
    const long long* wsm  = (const long long*)d_in[3];
    const int S = in_sizes[2];
    float* partial = (float*)d_ws;   // N * gridX * 16 floats (= 64 KB at S=1000)
    float* out = (float*)d_out;

    dim3 grid((S + 3) / 4, NN);
    ncut_accum<<<grid, 256, 0, stream>>>(pred, imgs, hs, wsm, partial, S, grid.x);
    ncut_final<<<1, 256, 0, stream>>>(partial, out, grid.x);
}

// Round 4
// 27.327 us; speedup vs baseline: 1.3006x; 1.3006x over previous
//
#include <hip/hip_runtime.h>

// NcutLoss: N=4, K=8, C=3, H=W=1024, S=1000, R=5, P=81 disk points.
// loss = N*K - sum_{n,k} num[n,k]/den[n,k]
//   num[n,k] = sum_{s,p} wgt[n,s,p]*q[n,k,s,p]*pc[n,k,s]
//   den[n,k] = sum_s pc[n,k,s] * sum_p wgt[n,s,p]
//   wgt = exp(-d2/SIGMA_I^2 - (di^2+dj^2)/SIGMA_X^2), d2 = sum_c (img_n-img_c)^2
//
// R3 change (base = R1, the fastest measured): each (n,s) is split across TWO
// waves by k-half (pred k=0-3 vs k=4-7). Both waves redundantly compute the
// img gather + exp; wave B passes its 4 sums via LDS. 8000 waves (~31/CU)
// to double memory-level parallelism and halve per-wave latency exposure.

constexpr int P = 81;
constexpr int WW = 1024;
constexpr size_t HW = (size_t)1024 * 1024;
constexpr int NN = 4, KK = 8, CC = 3;
constexpr int NSTRIPE = 64;
constexpr float INV_SI2 = 1.0f / 100.0f;  // 1/SIGMA_I^2
constexpr float INV_SX2 = 1.0f / 16.0f;   // 1/SIGMA_X^2

// Disk offsets, row-major over di=-5..5 (order irrelevant: all sums over p).
__device__ __constant__ signed char c_di[P] = {
    -5,
    -4,-4,-4,-4,-4,-4,-4,
    -3,-3,-3,-3,-3,-3,-3,-3,-3,
    -2,-2,-2,-2,-2,-2,-2,-2,-2,
    -1,-1,-1,-1,-1,-1,-1,-1,-1,
     0, 0, 0, 0, 0, 0, 0, 0, 0, 0, 0,
     1, 1, 1, 1, 1, 1, 1, 1, 1,
     2, 2, 2, 2, 2, 2, 2, 2, 2,
     3, 3, 3, 3, 3, 3, 3, 3, 3,
     4, 4, 4, 4, 4, 4, 4,
     5
};
__device__ __constant__ signed char c_dj[P] = {
     0,
    -3,-2,-1, 0, 1, 2, 3,
    -4,-3,-2,-1, 0, 1, 2, 3, 4,
    -4,-3,-2,-1, 0, 1, 2, 3, 4,
    -4,-3,-2,-1, 0, 1, 2, 3, 4,
    -5,-4,-3,-2,-1, 0, 1, 2, 3, 4, 5,
    -4,-3,-2,-1, 0, 1, 2, 3, 4,
    -4,-3,-2,-1, 0, 1, 2, 3, 4,
    -4,-3,-2,-1, 0, 1, 2, 3, 4,
    -3,-2,-1, 0, 1, 2, 3,
     0
};

__global__ void ncut_zero(float* __restrict__ acc) {
    const int i = blockIdx.x * blockDim.x + threadIdx.x;
    if (i < NSTRIPE * 64) acc[i] = 0.0f;
}

__global__ __launch_bounds__(256) void ncut_accum(
    const float* __restrict__ pred,   // (N,K,H,W)
    const float* __restrict__ imgs,   // (N,C,H,W)
    const long long* __restrict__ hs, // (S,)
    const long long* __restrict__ wsm,// (S,)
    float* __restrict__ acc,          // NSTRIPE x 64 floats
    int S)
{
    __shared__ float xqw[2][4];       // wave-B k=4..7 sums per local sample
    __shared__ float lbin[16];        // block bins: num[8], den[8]
    const int tid   = threadIdx.x;
    const int lane  = tid & 63;
    const int wv    = tid >> 6;       // 0..3
    const int sl    = wv >> 1;        // local sample 0..1
    const int khalf = wv & 1;         // 0: k=0..3 + epilogue, 1: k=4..7
    if (tid < 16) lbin[tid] = 0.0f;
    __syncthreads();

    const int n = blockIdx.y;
    const int s = blockIdx.x * 2 + sl;
    const bool act = (s < S);

    const float* pn = nullptr;
    size_t coff = 0;
    float wsum = 0.0f;
    float qw[4] = {0.f, 0.f, 0.f, 0.f};

    if (act) {
        const int h = (int)hs[s] + 5;
        const int w = (int)wsm[s] + 5;
        const float* img_n = imgs + (size_t)n * CC * HW;
        coff = (size_t)h * WW + w;
        pn = pred + (size_t)n * KK * HW;
        const float* pk = pn + (size_t)(khalf * 4) * HW;

        const float c0 = img_n[coff];
        const float c1 = img_n[HW + coff];
        const float c2 = img_n[2 * HW + coff];

        #pragma unroll
        for (int rep = 0; rep < 2; ++rep) {
            const int p = lane + rep * 64;
            if (p < P) {
                const int di = (int)c_di[p];
                const int dj = (int)c_dj[p];
                const size_t off = (size_t)(h + di) * WW + (w + dj);
                const float d0 = img_n[off]          - c0;
                const float d1 = img_n[HW + off]     - c1;
                const float d2 = img_n[2 * HW + off] - c2;
                const float r2 = (float)(di * di + dj * dj);
                const float wgt = __expf(-((d0*d0 + d1*d1 + d2*d2) * INV_SI2
                                           + r2 * INV_SX2));
                wsum += wgt;
                const float* qb = pk + off;
                #pragma unroll
                for (int j = 0; j < 4; ++j)
                    qw[j] += wgt * qb[(size_t)j * HW];
            }
        }

        // 64-lane butterfly over 5 values.
        #pragma unroll
        for (int off = 32; off; off >>= 1) {
            wsum += __shfl_xor(wsum, off);
            #pragma unroll
            for (int j = 0; j < 4; ++j)
                qw[j] += __shfl_xor(qw[j], off);
        }

        if (khalf == 1 && lane == 0) {
            xqw[sl][0] = qw[0]; xqw[sl][1] = qw[1];
            xqw[sl][2] = qw[2]; xqw[sl][3] = qw[3];
        }
    }
    __syncthreads();

    if (act && khalf == 0 && lane == 0) {
        const float* pc = pn + coff;
        float pv[KK];
        #pragma unroll
        for (int k = 0; k < KK; ++k)
            pv[k] = pc[(size_t)k * HW];
        #pragma unroll
        for (int j = 0; j < 4; ++j) {
            atomicAdd(&lbin[j],     pv[j]     * qw[j]);
            atomicAdd(&lbin[4 + j], pv[4 + j] * xqw[sl][j]);
        }
        #pragma unroll
        for (int k = 0; k < KK; ++k)
            atomicAdd(&lbin[8 + k], pv[k] * wsum);
    }
    __syncthreads();

    // Striped global accumulation (R1 pattern): stripe per block.
    if (tid < KK) {
        float* st = acc + (size_t)(blockIdx.x & (NSTRIPE - 1)) * 64;
        atomicAdd(&st[n * KK + tid],      lbin[tid]);
        atomicAdd(&st[32 + n * KK + tid], lbin[8 + tid]);
    }
}

__global__ void ncut_final(const float* __restrict__ acc, float* __restrict__ out) {
    const int tid = threadIdx.x;  // 64 threads: tid<32 num slots, tid>=32 den slots
    float v = 0.0f;
    #pragma unroll 8
    for (int st = 0; st < NSTRIPE; ++st)
        v += acc[st * 64 + tid];
    const float den = __shfl_xor(v, 32);     // lane t<32 gets matching den
    float r = (tid < 32) ? v / den : 0.0f;
    #pragma unroll
    for (int off = 32; off; off >>= 1)
        r += __shfl_xor(r, off);
    if (tid == 0) out[0] = (float)(NN * KK) - r;
}

extern "C" void kernel_launch(void* const* d_in, const int* in_sizes, int n_in,
                              void* d_out, int out_size, void* d_ws, size_t ws_size,
                              hipStream_t stream) {
    const float* pred     = (const float*)d_in[0];
    const float* imgs     = (const float*)d_in[1];
    const long long* hs   = (const long long*)d_in[2];
    const long long* wsm  = (const long long*)d_in[3];
    const int S = in_sizes[2];
    float* acc = (float*)d_ws;   // NSTRIPE * 64 floats = 16 KB
    float* out = (float*)d_out;

    ncut_zero<<<(NSTRIPE * 64 + 255) / 256, 256, 0, stream>>>(acc);
    dim3 grid((S + 1) / 2, NN);   // 2 samples per block (4 waves, 2 per sample)
    ncut_accum<<<grid, 256, 0, stream>>>(pred, imgs, hs, wsm, acc, S);
    ncut_final<<<1, 64, 0, stream>>>(acc, out);
}